// Round 16
// baseline (1446.449 us; speedup 1.0000x reference)
//
#include <hip/hip_runtime.h>

#define NVARS    12000
#define NNODES   8400
#define NLEAF    3600
#define NROUNDS  12
#define RPB      48              // rows per block (best weight amortization)
#define NB       250             // blocks (250*48 = 12000; node boundary = 175*48)
#define NODE_BLKS 175
#define CAP      64              // CSR fan-in cap (mean ~10, P(>64) ~ 0)
#define TPB      512             // 8 waves: wave w owns 16 output cols (B loaded once/block)
#define CTPB     256             // prologue block size

typedef _Float16 f16;
typedef _Float16 half8 __attribute__((ext_vector_type(8)));
typedef _Float16 half4v __attribute__((ext_vector_type(4)));
typedef float f32x4 __attribute__((ext_vector_type(4)));
typedef unsigned long long ull;

#define MROW 136                 // LDS plane row stride in halves (272B, 16B-aligned)
#define PLANE (RPB * MROW)       // 6528 halves per plane

struct Params {
    f16 *t1a, *t1b;              // fp16 message buffers (r15: halved IF traffic)
    int *bar;
    const int *vt, *ncnt, *nidx, *vcnt, *vidx;
    const float *true_w, *true_b, *false_w, *false_b;
    const f16 *wm_hi;                  // 8 MLP mats [n=128][k=128] fp16
    const f16 *vu_hi;                  // [512][256] (k<128: wih, k>=128: whh)
    const f16 *nu_hi;
    const float *cm_b1, *cm_b2, *cm_b3, *pm_b1, *pm_b2, *pm_b3;
    const float *vv_b1, *vv_b2, *vv_w3, *vv_b3;
    const float *vu_bih, *vu_bhh, *nu_bih, *nu_bhh;
    float *out;
};

// fast transcendentals: v_exp_f32 + v_rcp_f32 (~1-2ulp; error ~1e-6 << budget)
__device__ __forceinline__ float sigm(float x) {
    return __builtin_amdgcn_rcpf(1.f + __expf(-x));
}
__device__ __forceinline__ float tanhfast(float x) {
    float e = __expf(-2.f * fabsf(x));          // in (0,1], overflow-safe
    float r = (1.f - e) * __builtin_amdgcn_rcpf(1.f + e);
    return x < 0.f ? -r : r;
}

// ---- software grid barrier, FENCELESS (proven r3). Sharded arrivals,
// LOAD-only agent-scope spin; vmcnt(0) drain before s_barrier publishes all
// agent-scope t1 stores.
__device__ __forceinline__ void gsync(int* bar, int target) {
    __builtin_amdgcn_s_waitcnt(0);
    __syncthreads();
    if (threadIdx.x == 0) {
        __hip_atomic_fetch_add(&bar[(blockIdx.x & 7) << 4], 1,
                               __ATOMIC_RELAXED, __HIP_MEMORY_SCOPE_AGENT);
        for (;;) {
            int s = 0;
#pragma unroll
            for (int k = 0; k < 8; ++k)
                s += __hip_atomic_load(&bar[k << 4], __ATOMIC_RELAXED,
                                       __HIP_MEMORY_SCOPE_AGENT);
            if (s >= target) break;   // monotone counters: no false positive
            __builtin_amdgcn_s_sleep(2);
        }
    }
    __syncthreads();
}

// Precision scheme: weights fp16 (r9); feed-forward activations fp16 (r10);
// t1 messages fp16 (r15); h plain fp16 (this round's probe -- hLo dropped);
// c fp32, all accums fp32.

// ---- B-fragment loader (gatesL gate tile: 8x half8 = 32 VGPRs)
__device__ __forceinline__ void loadB8(const f16* W, int gcol, int quad, half8* B) {
#pragma unroll
    for (int s = 0; s < 8; ++s)
        B[s] = *(const half8*)(W + (size_t)gcol * 256 + s * 32 + quad * 8);
}

// ---- one 128->128 MLP layer, A = single fp16 plane (ALL layers now).
__device__ void layerM1(const f16* inP,
                        const f16* Wh, const float* bias, bool relu, f16* outP) {
    const int lane = threadIdx.x & 63, l15 = lane & 15, quad = lane >> 4;
    const int w = threadIdx.x >> 6;          // 0..7
    half8 Bh[4];
#pragma unroll
    for (int s = 0; s < 4; ++s) {
        size_t off = (size_t)(w * 16 + l15) * 128 + s * 32 + quad * 8;
        Bh[s] = *(const half8*)(Wh + off);
    }
    const float b0 = bias[w * 16 + l15];
    const int col = w * 16 + l15;
#pragma unroll
    for (int mt = 0; mt < 3; ++mt) {
        half8 Ah[4];
#pragma unroll
        for (int s = 0; s < 4; ++s) {
            int off = (mt * 16 + l15) * MROW + s * 32 + quad * 8;
            Ah[s] = *(const half8*)(inP + off);
        }
        f32x4 acc = {0.f, 0.f, 0.f, 0.f};
#pragma unroll
        for (int s = 0; s < 4; ++s)
            acc = __builtin_amdgcn_mfma_f32_16x16x32_f16(Ah[s], Bh[s], acc, 0, 0, 0);
#pragma unroll
        for (int reg = 0; reg < 4; ++reg) {
            int row = mt * 16 + quad * 4 + reg;
            float v = acc[reg] + b0;
            if (relu) v = fmaxf(v, 0.f);
            outP[row * MROW + col] = (f16)v;
        }
    }
    __syncthreads();
}

// ---- copy a finished fp16 plane to global t1 (agent-scope, wide 8B stores,
// fully coalesced: 1536 ull, 3 per thread).
__device__ void storeT1(const f16* src, f16* dst, int R0) {
#pragma unroll
    for (int i = 0; i < 3; ++i) {
        int idx = threadIdx.x + i * TPB;     // 0..1535
        int r = idx >> 5, u = idx & 31;      // 32 ull per 128-half row
        ull v = *(const ull*)(src + r * MROW + u * 4);
        __hip_atomic_store((ull*)dst + (size_t)(R0 + r) * 32 + u, v,
                           __ATOMIC_RELAXED, __HIP_MEMORY_SCOPE_AGENT);
    }
    // no barrier needed: gsync follows immediately and drains vmem
}

// ---- LSTM over the block's 48 rows: A=[msg(fp16); h(fp16)] (K=256),
// 512 gate cols. Wave w owns h-cols [w*16,w*16+16) of EACH gate ->
// pointwise in-register. hLo dropped: 96 MFMA/wave (was 144), h LDS reads
// cut 1/3, pointwise writes h once.
__device__ void gatesL(const f16* msgP, f16* hP, float* cF,
                       const f16* Wh, const float* bih, const float* bhh) {
    const int lane = threadIdx.x & 63, l15 = lane & 15, quad = lane >> 4;
    const int w = threadIdx.x >> 6;          // 0..7
    const int col = w * 16 + l15;
    float gb[4];
#pragma unroll
    for (int g = 0; g < 4; ++g)
        gb[g] = bih[g * 128 + col] + bhh[g * 128 + col];
    f32x4 acc[3][4];
#pragma unroll
    for (int mt = 0; mt < 3; ++mt)
#pragma unroll
        for (int g = 0; g < 4; ++g)
            acc[mt][g] = (f32x4){0.f, 0.f, 0.f, 0.f};

    for (int g = 0; g < 4; ++g) {
        half8 Bh[8];
        loadB8(Wh, g * 128 + col, quad, Bh);
#pragma unroll
        for (int mt = 0; mt < 3; ++mt) {
            half8 Am[4], Ah[4];
#pragma unroll
            for (int s = 0; s < 4; ++s) {
                int off = (mt * 16 + l15) * MROW + s * 32 + quad * 8;
                Am[s] = *(const half8*)(msgP + off);
                Ah[s] = *(const half8*)(hP + off);
            }
#pragma unroll
            for (int s = 0; s < 4; ++s)       // K 0..127: msg
                acc[mt][g] = __builtin_amdgcn_mfma_f32_16x16x32_f16(Am[s], Bh[s], acc[mt][g], 0, 0, 0);
#pragma unroll
            for (int s = 0; s < 4; ++s)       // K 128..255: h
                acc[mt][g] = __builtin_amdgcn_mfma_f32_16x16x32_f16(Ah[s], Bh[s + 4], acc[mt][g], 0, 0, 0);
        }
    }
    __syncthreads();   // all waves' A-reads of h done before pointwise rewrites h
#pragma unroll
    for (int mt = 0; mt < 3; ++mt) {
#pragma unroll
        for (int reg = 0; reg < 4; ++reg) {
            int row = mt * 16 + quad * 4 + reg;
            float gi = acc[mt][0][reg] + gb[0];
            float gf = acc[mt][1][reg] + gb[1];
            float gg = acc[mt][2][reg] + gb[2];
            float go = acc[mt][3][reg] + gb[3];
            float cv = cF[row * 128 + col];
            float cn = sigm(gf) * cv + sigm(gi) * tanhfast(gg);
            float hn = sigm(go) * tanhfast(cn);
            cF[row * 128 + col] = cn;
            hP[row * MROW + col] = (f16)hn;
        }
    }
    __syncthreads();
}

// ---- gather helpers: agent-scope 8B loads of fp16 data (bypass local L2)
__device__ __forceinline__ void ld4h(ull* B, const f16* t1g, int idx, int q) {
    const ull* s = (const ull*)(t1g + (size_t)idx * 128) + q * 4;
#pragma unroll
    for (int u = 0; u < 4; ++u)
        B[u] = __hip_atomic_load(s + u, __ATOMIC_RELAXED, __HIP_MEMORY_SCOPE_AGENT);
}
__device__ __forceinline__ void acc4h(float* a, const ull* B) {
#pragma unroll
    for (int u = 0; u < 4; ++u) {
        union { ull q; f16 h[4]; } cv; cv.q = B[u];
#pragma unroll
        for (int k = 0; k < 4; ++k)
            a[u * 4 + k] += (float)cv.h[k];
    }
}

// ---- gather own 48 rows from global t1 (fp16) into the msg plane (fp16).
// 8 threads/row x 48 rows = 384 of 512 threads; thread q covers halves
// q*16..q*16+15. 4-deep ping-pong pipeline, j-order fp32 accumulation.
__device__ void gatherP(const f16* t1g, const int* cnt, const int* idxm,
                        f16* msgP, int R0) {
    if (threadIdx.x < 8 * RPB) {
        int r = threadIdx.x >> 3, q = threadIdx.x & 7;
        int row = R0 + r;
        int n = cnt[row]; if (n > CAP) n = CAP;
        const int* ir = idxm + (size_t)row * CAP;
        float a[16];
#pragma unroll
        for (int u = 0; u < 16; ++u) a[u] = 0.f;
        ull b0[4], b1[4], b2[4], b3[4];
        if (n > 0) ld4h(b0, t1g, ir[0], q);
        if (n > 1) ld4h(b1, t1g, ir[1], q);
        if (n > 2) ld4h(b2, t1g, ir[2], q);
        if (n > 3) ld4h(b3, t1g, ir[3], q);
        for (int j = 0; j < n; j += 4) {
            acc4h(a, b0);
            if (j + 4 < n) ld4h(b0, t1g, ir[j + 4], q);
            if (j + 1 < n) {
                acc4h(a, b1);
                if (j + 5 < n) ld4h(b1, t1g, ir[j + 5], q);
            }
            if (j + 2 < n) {
                acc4h(a, b2);
                if (j + 6 < n) ld4h(b2, t1g, ir[j + 6], q);
            }
            if (j + 3 < n) {
                acc4h(a, b3);
                if (j + 7 < n) ld4h(b3, t1g, ir[j + 7], q);
            }
        }
#pragma unroll
        for (int u4 = 0; u4 < 4; ++u4) {
            half4v hh;
#pragma unroll
            for (int k = 0; k < 4; ++k)
                hh[k] = (f16)a[u4 * 4 + k];
            int off = r * MROW + q * 16 + u4 * 4;
            *(half4v*)(msgP + off) = hh;
        }
    }
    __syncthreads();
}

// ---------------------------------------------------------------------------
// launch_bounds(512,1): 1 block/CU, 8 waves (2/SIMD). NB=250 <= 256 CUs ->
// co-resident, grid barrier safe. LDS 62KB (3 planes + cF).
__global__ void __launch_bounds__(TPB, 1) mega(Params p) {
    __shared__ __align__(16) f16 smh[3 * PLANE];       // 39168 B (h, a, b)
    __shared__ __align__(16) float cF[RPB * 128];      // 24576 B
    f16 *hP = smh, *aP = smh + PLANE, *bP = smh + 2 * PLANE;

    const int R0 = blockIdx.x * RPB;
    const bool isNode = blockIdx.x < NODE_BLKS;

    // init own rows: h0 = vt ? (tw+tb) : (fw+fb); c0 = 0
#pragma unroll
    for (int i = 0; i < (RPB * 128) / TPB; ++i) {
        int e = threadIdx.x + i * TPB;          // 0..6143
        int r = e >> 7, d = e & 127;
        float hv = (p.vt[R0 + r] == 1) ? (p.true_w[d] + p.true_b[d])
                                       : (p.false_w[d] + p.false_b[d]);
        hP[r * MROW + d] = (f16)hv;
        cF[r * 128 + d] = 0.f;
    }
    __syncthreads();

    int ep = 0;
    for (int rd = 0; rd < NROUNDS; ++rd) {
        // cm MLP on own rows -> aP plane -> t1a (wide coalesced stores)
        layerM1(hP, p.wm_hi + 0 * 16384, p.cm_b1, true,  aP);
        layerM1(aP, p.wm_hi + 1 * 16384, p.cm_b2, true,  bP);
        layerM1(bP, p.wm_hi + 2 * 16384, p.cm_b3, false, aP);
        storeT1(aP, p.t1a, R0);
        gsync(p.bar, ++ep * NB);
        if (isNode) {
            gatherP(p.t1a, p.ncnt, p.nidx, aP, R0);
            gatesL(aP, hP, cF, p.vu_hi, p.vu_bih, p.vu_bhh);
            // pm MLP on own (node) rows -> t1b
            layerM1(hP, p.wm_hi + 3 * 16384, p.pm_b1, true,  aP);
            layerM1(aP, p.wm_hi + 4 * 16384, p.pm_b2, true,  bP);
            layerM1(bP, p.wm_hi + 5 * 16384, p.pm_b3, false, aP);
            storeT1(aP, p.t1b, R0);
        }
        gsync(p.bar, ++ep * NB);
        gatherP(p.t1b, p.vcnt, p.vidx, aP, R0);
        gatesL(aP, hP, cF, p.nu_hi, p.nu_bih, p.nu_bhh);
    }

    // vote on leaf blocks (4 threads/row, 32 cols each: same reduction order)
    if (!isNode) {
        layerM1(hP, p.wm_hi + 6 * 16384, p.vv_b1, true, aP);
        layerM1(aP, p.wm_hi + 7 * 16384, p.vv_b2, true, bP);
        if (threadIdx.x < 4 * RPB) {
            int r = threadIdx.x >> 2, q = threadIdx.x & 3;
            float s = 0.f;
#pragma unroll
            for (int u = 0; u < 32; ++u) {
                int col = q * 32 + u;
                s += (float)bP[r * MROW + col] * p.vv_w3[col];
            }
            s += __shfl_xor(s, 1);
            s += __shfl_xor(s, 2);
            if (q == 0) p.out[R0 - NNODES + r] = s + p.vv_b3[0];
        }
    }
}

// ---------------------------------------------------------------------------
// Merged prologue (r12): CSR build + all weight conversions in one kernel.
struct BuildAll {
    const unsigned int* up;
    int *ncnt, *nidx, *vcnt, *vidx;
    const float* msrc[8];
    const float *vu_wih, *vu_whh, *nu_wih, *nu_whh;
    f16 *wm, *vu, *nu;
};

__global__ void build_all(BuildAll a) {
    const int b = blockIdx.x;
    if (b < NNODES) {
        __shared__ int cnt;
        if (threadIdx.x == 0) cnt = 0;
        __syncthreads();
        const uint4* row = (const uint4*)(a.up + (size_t)b * NVARS);
        for (int c = threadIdx.x; c < NVARS / 4; c += CTPB) {
            uint4 w = row[c];
            if ((w.x | w.y | w.z | w.w) == 0u) continue;
            unsigned e[4] = { w.x, w.y, w.z, w.w };
#pragma unroll
            for (int j = 0; j < 4; ++j) {
                if (e[j]) {
                    int v = c * 4 + j;
                    int s1 = atomicAdd(&cnt, 1);               // LDS atomic
                    if (s1 < CAP) a.nidx[b * CAP + s1] = v;
                    int s2 = atomicAdd(&a.vcnt[v], 1);         // global atomic
                    if (s2 < CAP) a.vidx[v * CAP + s2] = b;
                }
            }
        }
        __syncthreads();
        if (threadIdx.x == 0) a.ncnt[b] = cnt;
    } else {
        int idx = (b - NNODES) * CTPB + threadIdx.x;           // 0..393215
        if (idx < 131072) {
            a.wm[idx] = (f16)a.msrc[idx >> 14][idx & 16383];
        } else if (idx < 262144) {
            int i2 = idx - 131072;
            int n = i2 >> 8, k = i2 & 255;
            float x = (k < 128) ? a.vu_wih[n * 128 + k] : a.vu_whh[n * 128 + (k - 128)];
            a.vu[i2] = (f16)x;
        } else {
            int i2 = idx - 262144;
            int n = i2 >> 8, k = i2 & 255;
            float x = (k < 128) ? a.nu_wih[n * 128 + k] : a.nu_whh[n * 128 + (k - 128)];
            a.nu[i2] = (f16)x;
        }
    }
}

// ---------------------------------------------------------------------------
extern "C" void kernel_launch(void* const* d_in, const int* in_sizes, int n_in,
                              void* d_out, int out_size, void* d_ws, size_t ws_size,
                              hipStream_t stream) {
    Params p;
    p.vt      = (const int*)d_in[0];
    p.true_w  = (const float*)d_in[2];
    p.true_b  = (const float*)d_in[3];
    p.false_w = (const float*)d_in[4];
    p.false_b = (const float*)d_in[5];
    p.cm_b1 = (const float*)d_in[7];  p.cm_b2 = (const float*)d_in[9];
    p.cm_b3 = (const float*)d_in[11];
    p.pm_b1 = (const float*)d_in[13]; p.pm_b2 = (const float*)d_in[15];
    p.pm_b3 = (const float*)d_in[17];
    p.vv_b1 = (const float*)d_in[19]; p.vv_b2 = (const float*)d_in[21];
    p.vv_w3 = (const float*)d_in[22]; p.vv_b3 = (const float*)d_in[23];
    p.vu_bih = (const float*)d_in[26]; p.vu_bhh = (const float*)d_in[27];
    p.nu_bih = (const float*)d_in[30]; p.nu_bhh = (const float*)d_in[31];

    // workspace layout (t1 fp16)
    f16* t1a = (f16*)d_ws;                       // [12000][128] f16
    f16* t1b = t1a + (size_t)NVARS * 128;        // [12000][128] f16
    int* ncnt = (int*)(t1b + (size_t)NVARS * 128);
    int* nidx = ncnt + NNODES;                   // [NNODES][CAP]
    int* vcnt = nidx + NNODES * CAP;
    int* vidx = vcnt + NVARS;                    // [NVARS][CAP]
    int* bar  = vidx + NVARS * CAP;              // 8 sharded counters, 64B apart
    uintptr_t wb = (uintptr_t)(bar + 128);
    wb = (wb + 15) & ~(uintptr_t)15;
    f16* wm_hi = (f16*)wb;            // 8*16384
    f16* vu_hi = wm_hi + 131072;      // 512*256
    f16* nu_hi = vu_hi + 131072;

    p.t1a = t1a; p.t1b = t1b; p.bar = bar;
    p.ncnt = ncnt; p.nidx = nidx; p.vcnt = vcnt; p.vidx = vidx;
    p.wm_hi = wm_hi; p.vu_hi = vu_hi; p.nu_hi = nu_hi;
    p.out = (float*)d_out;

    (void)hipMemsetAsync(vcnt, 0, NVARS * sizeof(int), stream);
    (void)hipMemsetAsync(bar, 0, 128 * sizeof(int), stream);

    BuildAll ba;
    ba.up = (const unsigned int*)d_in[1];
    ba.ncnt = ncnt; ba.nidx = nidx; ba.vcnt = vcnt; ba.vidx = vidx;
    ba.msrc[0] = (const float*)d_in[6];  ba.msrc[1] = (const float*)d_in[8];
    ba.msrc[2] = (const float*)d_in[10]; ba.msrc[3] = (const float*)d_in[12];
    ba.msrc[4] = (const float*)d_in[14]; ba.msrc[5] = (const float*)d_in[16];
    ba.msrc[6] = (const float*)d_in[18]; ba.msrc[7] = (const float*)d_in[20];
    ba.vu_wih = (const float*)d_in[24]; ba.vu_whh = (const float*)d_in[25];
    ba.nu_wih = (const float*)d_in[28]; ba.nu_whh = (const float*)d_in[29];
    ba.wm = wm_hi; ba.vu = vu_hi; ba.nu = nu_hi;
    build_all<<<NNODES + 1536, CTPB, 0, stream>>>(ba);

    mega<<<NB, TPB, 0, stream>>>(p);
}

// Round 17
// 1348.763 us; speedup vs baseline: 1.0724x; 1.0724x over previous
//
#include <hip/hip_runtime.h>

#define NVARS    12000
#define NNODES   8400
#define NLEAF    3600
#define NROUNDS  12
#define RPB      48              // rows per block (best weight amortization)
#define NB       250             // blocks (250*48 = 12000; node boundary = 175*48)
#define NODE_BLKS 175
#define CAP      64              // CSR fan-in cap (mean ~10, P(>64) ~ 0)
#define TPB      512             // 8 waves: wave w owns 16 output cols (B loaded once/block)
#define CTPB     256             // prologue block size

typedef _Float16 f16;
typedef _Float16 half8 __attribute__((ext_vector_type(8)));
typedef _Float16 half4v __attribute__((ext_vector_type(4)));
typedef float f32x4 __attribute__((ext_vector_type(4)));
typedef unsigned long long ull;

#define MROW 136                 // LDS plane row stride in halves (272B, 16B-aligned)
#define PLANE (RPB * MROW)       // 6528 halves per plane

struct Params {
    f16 *t1a, *t1b;              // fp16 message buffers (r15: halved IF traffic)
    int *bar;
    const int *vt, *ncnt, *nidx, *vcnt, *vidx;
    const float *true_w, *true_b, *false_w, *false_b;
    const f16 *wm_hi;                  // 8 MLP mats [n=128][k=128] fp16
    const f16 *vu_hi;                  // [512][256] (k<128: wih, k>=128: whh)
    const f16 *nu_hi;
    const float *cm_b1, *cm_b2, *cm_b3, *pm_b1, *pm_b2, *pm_b3;
    const float *vv_b1, *vv_b2, *vv_w3, *vv_b3;
    const float *vu_bih, *vu_bhh, *nu_bih, *nu_bhh;
    float *out;
};

// fast transcendentals via v_exp_f32 (~2ulp; error ~1e-6 << 2e-3 budget)
__device__ __forceinline__ float sigm(float x) { return 1.f / (1.f + __expf(-x)); }
__device__ __forceinline__ float tanhfast(float x) {
    float e = __expf(-2.f * fabsf(x));          // in (0,1], overflow-safe
    float r = (1.f - e) / (1.f + e);
    return x < 0.f ? -r : r;
}

// ---- software grid barrier, FENCELESS (r3), BROADCAST-RELEASE (this round).
// Arrivals: sharded agent-scope atomicAdd (8 cachelines), preceded by a
// vmcnt(0) drain that publishes all agent-scope t1 stores. Release: ONLY
// block 0's leader sums the shards; it then stores the epoch number to one
// release word, and the other 249 leaders spin on that single line (one IF
// line served broadcast-style, one load to observe -- vs 250 leaders each
// serially summing 8 lines in the r15 version).
__device__ __forceinline__ void gsync(int* bar, int epno) {
    __builtin_amdgcn_s_waitcnt(0);
    __syncthreads();
    if (threadIdx.x == 0) {
        __hip_atomic_fetch_add(&bar[(blockIdx.x & 7) << 4], 1,
                               __ATOMIC_RELAXED, __HIP_MEMORY_SCOPE_AGENT);
        if (blockIdx.x == 0) {
            const int target = epno * NB;
            for (;;) {
                int s = 0;
#pragma unroll
                for (int k = 0; k < 8; ++k)
                    s += __hip_atomic_load(&bar[k << 4], __ATOMIC_RELAXED,
                                           __HIP_MEMORY_SCOPE_AGENT);
                if (s >= target) break;   // monotone counters: no false positive
                __builtin_amdgcn_s_sleep(2);
            }
            __hip_atomic_store(&bar[128], epno, __ATOMIC_RELAXED,
                               __HIP_MEMORY_SCOPE_AGENT);
        } else {
            while (__hip_atomic_load(&bar[128], __ATOMIC_RELAXED,
                                     __HIP_MEMORY_SCOPE_AGENT) < epno)
                __builtin_amdgcn_s_sleep(2);
        }
    }
    __syncthreads();
}

// Precision scheme: weights fp16 (r9); feed-forward activations fp16 (r10);
// t1 messages fp16 (r15); recurrent h hi/lo split, c fp32, accums fp32.
// (r16's h-fp16 probe reverted: numerically fine but spilled at the 128-VGPR
// compiler wall -- third spill from a different direction.)

// ---- B-fragment loader (gatesL gate tile: 8x half8 = 32 VGPRs)
__device__ __forceinline__ void loadB8(const f16* W, int gcol, int quad, half8* B) {
#pragma unroll
    for (int s = 0; s < 8; ++s)
        B[s] = *(const half8*)(W + (size_t)gcol * 256 + s * 32 + quad * 8);
}

// ---- one 128->128 MLP layer, A = hi/lo planes (layer 1 reading h).
__device__ void layerM2(const f16* inHi, const f16* inLo,
                        const f16* Wh, const float* bias, bool relu, f16* outP) {
    const int lane = threadIdx.x & 63, l15 = lane & 15, quad = lane >> 4;
    const int w = threadIdx.x >> 6;          // 0..7
    half8 Bh[4];
#pragma unroll
    for (int s = 0; s < 4; ++s) {
        size_t off = (size_t)(w * 16 + l15) * 128 + s * 32 + quad * 8;
        Bh[s] = *(const half8*)(Wh + off);
    }
    const float b0 = bias[w * 16 + l15];
    const int col = w * 16 + l15;
#pragma unroll
    for (int mt = 0; mt < 3; ++mt) {
        half8 Ah[4], Al[4];
#pragma unroll
        for (int s = 0; s < 4; ++s) {
            int off = (mt * 16 + l15) * MROW + s * 32 + quad * 8;
            Ah[s] = *(const half8*)(inHi + off);
            Al[s] = *(const half8*)(inLo + off);
        }
        f32x4 acc = {0.f, 0.f, 0.f, 0.f};
#pragma unroll
        for (int s = 0; s < 4; ++s) {
            acc = __builtin_amdgcn_mfma_f32_16x16x32_f16(Ah[s], Bh[s], acc, 0, 0, 0);
            acc = __builtin_amdgcn_mfma_f32_16x16x32_f16(Al[s], Bh[s], acc, 0, 0, 0);
        }
#pragma unroll
        for (int reg = 0; reg < 4; ++reg) {
            int row = mt * 16 + quad * 4 + reg;
            float v = acc[reg] + b0;
            if (relu) v = fmaxf(v, 0.f);
            outP[row * MROW + col] = (f16)v;
        }
    }
    __syncthreads();
}

// ---- one 128->128 MLP layer, A = single fp16 plane (layers 2/3, vote).
__device__ void layerM1(const f16* inP,
                        const f16* Wh, const float* bias, bool relu, f16* outP) {
    const int lane = threadIdx.x & 63, l15 = lane & 15, quad = lane >> 4;
    const int w = threadIdx.x >> 6;          // 0..7
    half8 Bh[4];
#pragma unroll
    for (int s = 0; s < 4; ++s) {
        size_t off = (size_t)(w * 16 + l15) * 128 + s * 32 + quad * 8;
        Bh[s] = *(const half8*)(Wh + off);
    }
    const float b0 = bias[w * 16 + l15];
    const int col = w * 16 + l15;
#pragma unroll
    for (int mt = 0; mt < 3; ++mt) {
        half8 Ah[4];
#pragma unroll
        for (int s = 0; s < 4; ++s) {
            int off = (mt * 16 + l15) * MROW + s * 32 + quad * 8;
            Ah[s] = *(const half8*)(inP + off);
        }
        f32x4 acc = {0.f, 0.f, 0.f, 0.f};
#pragma unroll
        for (int s = 0; s < 4; ++s)
            acc = __builtin_amdgcn_mfma_f32_16x16x32_f16(Ah[s], Bh[s], acc, 0, 0, 0);
#pragma unroll
        for (int reg = 0; reg < 4; ++reg) {
            int row = mt * 16 + quad * 4 + reg;
            float v = acc[reg] + b0;
            if (relu) v = fmaxf(v, 0.f);
            outP[row * MROW + col] = (f16)v;
        }
    }
    __syncthreads();
}

// ---- copy a finished fp16 plane to global t1 (agent-scope, wide 8B stores,
// fully coalesced: 1536 ull, 3 per thread).
__device__ void storeT1(const f16* src, f16* dst, int R0) {
#pragma unroll
    for (int i = 0; i < 3; ++i) {
        int idx = threadIdx.x + i * TPB;     // 0..1535
        int r = idx >> 5, u = idx & 31;      // 32 ull per 128-half row
        ull v = *(const ull*)(src + r * MROW + u * 4);
        __hip_atomic_store((ull*)dst + (size_t)(R0 + r) * 32 + u, v,
                           __ATOMIC_RELAXED, __HIP_MEMORY_SCOPE_AGENT);
    }
    // no barrier needed: gsync follows immediately and drains vmem
}

// ---- LSTM over the block's 48 rows: A=[msg(fp16); h(hi/lo)] (K=256),
// 512 gate cols. Wave w owns h-cols [w*16,w*16+16) of EACH gate ->
// pointwise in-register. (r15 structure: the proven 834us shape.)
__device__ void gatesL(const f16* msgP, f16* hHi, f16* hLo, float* cF,
                       const f16* Wh, const float* bih, const float* bhh) {
    const int lane = threadIdx.x & 63, l15 = lane & 15, quad = lane >> 4;
    const int w = threadIdx.x >> 6;          // 0..7
    const int col = w * 16 + l15;
    float gb[4];
#pragma unroll
    for (int g = 0; g < 4; ++g)
        gb[g] = bih[g * 128 + col] + bhh[g * 128 + col];
    f32x4 acc[3][4];
#pragma unroll
    for (int mt = 0; mt < 3; ++mt)
#pragma unroll
        for (int g = 0; g < 4; ++g)
            acc[mt][g] = (f32x4){0.f, 0.f, 0.f, 0.f};

    for (int g = 0; g < 4; ++g) {
        half8 Bh[8];
        loadB8(Wh, g * 128 + col, quad, Bh);
#pragma unroll
        for (int mt = 0; mt < 3; ++mt) {
            half8 Am[4], Ah[4], Al[4];
#pragma unroll
            for (int s = 0; s < 4; ++s) {
                int off = (mt * 16 + l15) * MROW + s * 32 + quad * 8;
                Am[s] = *(const half8*)(msgP + off);
                Ah[s] = *(const half8*)(hHi + off);
                Al[s] = *(const half8*)(hLo + off);
            }
#pragma unroll
            for (int s = 0; s < 4; ++s)       // K 0..127: msg (fp16)
                acc[mt][g] = __builtin_amdgcn_mfma_f32_16x16x32_f16(Am[s], Bh[s], acc[mt][g], 0, 0, 0);
#pragma unroll
            for (int s = 0; s < 4; ++s) {     // K 128..255: h (hi/lo)
                acc[mt][g] = __builtin_amdgcn_mfma_f32_16x16x32_f16(Ah[s], Bh[s + 4], acc[mt][g], 0, 0, 0);
                acc[mt][g] = __builtin_amdgcn_mfma_f32_16x16x32_f16(Al[s], Bh[s + 4], acc[mt][g], 0, 0, 0);
            }
        }
    }
    __syncthreads();   // all waves' A-reads of h done before pointwise rewrites h
#pragma unroll
    for (int mt = 0; mt < 3; ++mt) {
#pragma unroll
        for (int reg = 0; reg < 4; ++reg) {
            int row = mt * 16 + quad * 4 + reg;
            float gi = acc[mt][0][reg] + gb[0];
            float gf = acc[mt][1][reg] + gb[1];
            float gg = acc[mt][2][reg] + gb[2];
            float go = acc[mt][3][reg] + gb[3];
            float cv = cF[row * 128 + col];
            float cn = sigm(gf) * cv + sigm(gi) * tanhfast(gg);
            float hn = sigm(go) * tanhfast(cn);
            cF[row * 128 + col] = cn;
            f16 hh = (f16)hn;
            hHi[row * MROW + col] = hh;
            hLo[row * MROW + col] = (f16)(hn - (float)hh);
        }
    }
    __syncthreads();
}

// ---- gather helpers: agent-scope 8B loads of fp16 data (bypass local L2)
__device__ __forceinline__ void ld4h(ull* B, const f16* t1g, int idx, int q) {
    const ull* s = (const ull*)(t1g + (size_t)idx * 128) + q * 4;
#pragma unroll
    for (int u = 0; u < 4; ++u)
        B[u] = __hip_atomic_load(s + u, __ATOMIC_RELAXED, __HIP_MEMORY_SCOPE_AGENT);
}
__device__ __forceinline__ void acc4h(float* a, const ull* B) {
#pragma unroll
    for (int u = 0; u < 4; ++u) {
        union { ull q; f16 h[4]; } cv; cv.q = B[u];
#pragma unroll
        for (int k = 0; k < 4; ++k)
            a[u * 4 + k] += (float)cv.h[k];
    }
}

// ---- gather own 48 rows from global t1 (fp16) into the msg plane (fp16).
// 8 threads/row x 48 rows = 384 of 512 threads; thread q covers halves
// q*16..q*16+15. 4-deep ping-pong pipeline, j-order fp32 accumulation.
__device__ void gatherP(const f16* t1g, const int* cnt, const int* idxm,
                        f16* msgP, int R0) {
    if (threadIdx.x < 8 * RPB) {
        int r = threadIdx.x >> 3, q = threadIdx.x & 7;
        int row = R0 + r;
        int n = cnt[row]; if (n > CAP) n = CAP;
        const int* ir = idxm + (size_t)row * CAP;
        float a[16];
#pragma unroll
        for (int u = 0; u < 16; ++u) a[u] = 0.f;
        ull b0[4], b1[4], b2[4], b3[4];
        if (n > 0) ld4h(b0, t1g, ir[0], q);
        if (n > 1) ld4h(b1, t1g, ir[1], q);
        if (n > 2) ld4h(b2, t1g, ir[2], q);
        if (n > 3) ld4h(b3, t1g, ir[3], q);
        for (int j = 0; j < n; j += 4) {
            acc4h(a, b0);
            if (j + 4 < n) ld4h(b0, t1g, ir[j + 4], q);
            if (j + 1 < n) {
                acc4h(a, b1);
                if (j + 5 < n) ld4h(b1, t1g, ir[j + 5], q);
            }
            if (j + 2 < n) {
                acc4h(a, b2);
                if (j + 6 < n) ld4h(b2, t1g, ir[j + 6], q);
            }
            if (j + 3 < n) {
                acc4h(a, b3);
                if (j + 7 < n) ld4h(b3, t1g, ir[j + 7], q);
            }
        }
#pragma unroll
        for (int u4 = 0; u4 < 4; ++u4) {
            half4v hh;
#pragma unroll
            for (int k = 0; k < 4; ++k)
                hh[k] = (f16)a[u4 * 4 + k];
            int off = r * MROW + q * 16 + u4 * 4;
            *(half4v*)(msgP + off) = hh;
        }
    }
    __syncthreads();
}

// ---------------------------------------------------------------------------
// launch_bounds(512,1): 1 block/CU, 8 waves (2/SIMD). NB=250 <= 256 CUs ->
// co-resident, grid barrier safe. LDS 77KB. (r15 structure verbatim.)
__global__ void __launch_bounds__(TPB, 1) mega(Params p) {
    __shared__ __align__(16) f16 smh[4 * PLANE];       // 52224 B (h hi/lo, a, b)
    __shared__ __align__(16) float cF[RPB * 128];      // 24576 B
    f16 *hHi = smh,             *hLo = smh + PLANE;
    f16 *aP  = smh + 2 * PLANE, *bP  = smh + 3 * PLANE;

    const int R0 = blockIdx.x * RPB;
    const bool isNode = blockIdx.x < NODE_BLKS;

    // init own rows: h0 = vt ? (tw+tb) : (fw+fb); c0 = 0
#pragma unroll
    for (int i = 0; i < (RPB * 128) / TPB; ++i) {
        int e = threadIdx.x + i * TPB;          // 0..6143
        int r = e >> 7, d = e & 127;
        float hv = (p.vt[R0 + r] == 1) ? (p.true_w[d] + p.true_b[d])
                                       : (p.false_w[d] + p.false_b[d]);
        f16 hh = (f16)hv;
        hHi[r * MROW + d] = hh;
        hLo[r * MROW + d] = (f16)(hv - (float)hh);
        cF[r * 128 + d] = 0.f;
    }
    __syncthreads();

    int ep = 0;
    for (int rd = 0; rd < NROUNDS; ++rd) {
        // cm MLP on own rows -> aP plane -> t1a (wide coalesced stores)
        layerM2(hHi, hLo, p.wm_hi + 0 * 16384, p.cm_b1, true,  aP);
        layerM1(aP,       p.wm_hi + 1 * 16384, p.cm_b2, true,  bP);
        layerM1(bP,       p.wm_hi + 2 * 16384, p.cm_b3, false, aP);
        storeT1(aP, p.t1a, R0);
        gsync(p.bar, ++ep);
        if (isNode) {
            gatherP(p.t1a, p.ncnt, p.nidx, aP, R0);
            gatesL(aP, hHi, hLo, cF, p.vu_hi, p.vu_bih, p.vu_bhh);
            // pm MLP on own (node) rows -> t1b
            layerM2(hHi, hLo, p.wm_hi + 3 * 16384, p.pm_b1, true,  aP);
            layerM1(aP,       p.wm_hi + 4 * 16384, p.pm_b2, true,  bP);
            layerM1(bP,       p.wm_hi + 5 * 16384, p.pm_b3, false, aP);
            storeT1(aP, p.t1b, R0);
        }
        gsync(p.bar, ++ep);
        gatherP(p.t1b, p.vcnt, p.vidx, aP, R0);
        gatesL(aP, hHi, hLo, cF, p.nu_hi, p.nu_bih, p.nu_bhh);
    }

    // vote on leaf blocks (4 threads/row, 32 cols each: same reduction order)
    if (!isNode) {
        layerM2(hHi, hLo, p.wm_hi + 6 * 16384, p.vv_b1, true, aP);
        layerM1(aP,       p.wm_hi + 7 * 16384, p.vv_b2, true, bP);
        if (threadIdx.x < 4 * RPB) {
            int r = threadIdx.x >> 2, q = threadIdx.x & 3;
            float s = 0.f;
#pragma unroll
            for (int u = 0; u < 32; ++u) {
                int col = q * 32 + u;
                s += (float)bP[r * MROW + col] * p.vv_w3[col];
            }
            s += __shfl_xor(s, 1);
            s += __shfl_xor(s, 2);
            if (q == 0) p.out[R0 - NNODES + r] = s + p.vv_b3[0];
        }
    }
}

// ---------------------------------------------------------------------------
// Merged prologue (r12): CSR build + all weight conversions in one kernel.
struct BuildAll {
    const unsigned int* up;
    int *ncnt, *nidx, *vcnt, *vidx;
    const float* msrc[8];
    const float *vu_wih, *vu_whh, *nu_wih, *nu_whh;
    f16 *wm, *vu, *nu;
};

__global__ void build_all(BuildAll a) {
    const int b = blockIdx.x;
    if (b < NNODES) {
        __shared__ int cnt;
        if (threadIdx.x == 0) cnt = 0;
        __syncthreads();
        const uint4* row = (const uint4*)(a.up + (size_t)b * NVARS);
        for (int c = threadIdx.x; c < NVARS / 4; c += CTPB) {
            uint4 w = row[c];
            if ((w.x | w.y | w.z | w.w) == 0u) continue;
            unsigned e[4] = { w.x, w.y, w.z, w.w };
#pragma unroll
            for (int j = 0; j < 4; ++j) {
                if (e[j]) {
                    int v = c * 4 + j;
                    int s1 = atomicAdd(&cnt, 1);               // LDS atomic
                    if (s1 < CAP) a.nidx[b * CAP + s1] = v;
                    int s2 = atomicAdd(&a.vcnt[v], 1);         // global atomic
                    if (s2 < CAP) a.vidx[v * CAP + s2] = b;
                }
            }
        }
        __syncthreads();
        if (threadIdx.x == 0) a.ncnt[b] = cnt;
    } else {
        int idx = (b - NNODES) * CTPB + threadIdx.x;           // 0..393215
        if (idx < 131072) {
            a.wm[idx] = (f16)a.msrc[idx >> 14][idx & 16383];
        } else if (idx < 262144) {
            int i2 = idx - 131072;
            int n = i2 >> 8, k = i2 & 255;
            float x = (k < 128) ? a.vu_wih[n * 128 + k] : a.vu_whh[n * 128 + (k - 128)];
            a.vu[i2] = (f16)x;
        } else {
            int i2 = idx - 262144;
            int n = i2 >> 8, k = i2 & 255;
            float x = (k < 128) ? a.nu_wih[n * 128 + k] : a.nu_whh[n * 128 + (k - 128)];
            a.nu[i2] = (f16)x;
        }
    }
}

// ---------------------------------------------------------------------------
extern "C" void kernel_launch(void* const* d_in, const int* in_sizes, int n_in,
                              void* d_out, int out_size, void* d_ws, size_t ws_size,
                              hipStream_t stream) {
    Params p;
    p.vt      = (const int*)d_in[0];
    p.true_w  = (const float*)d_in[2];
    p.true_b  = (const float*)d_in[3];
    p.false_w = (const float*)d_in[4];
    p.false_b = (const float*)d_in[5];
    p.cm_b1 = (const float*)d_in[7];  p.cm_b2 = (const float*)d_in[9];
    p.cm_b3 = (const float*)d_in[11];
    p.pm_b1 = (const float*)d_in[13]; p.pm_b2 = (const float*)d_in[15];
    p.pm_b3 = (const float*)d_in[17];
    p.vv_b1 = (const float*)d_in[19]; p.vv_b2 = (const float*)d_in[21];
    p.vv_w3 = (const float*)d_in[22]; p.vv_b3 = (const float*)d_in[23];
    p.vu_bih = (const float*)d_in[26]; p.vu_bhh = (const float*)d_in[27];
    p.nu_bih = (const float*)d_in[30]; p.nu_bhh = (const float*)d_in[31];

    // workspace layout (t1 fp16)
    f16* t1a = (f16*)d_ws;                       // [12000][128] f16
    f16* t1b = t1a + (size_t)NVARS * 128;        // [12000][128] f16
    int* ncnt = (int*)(t1b + (size_t)NVARS * 128);
    int* nidx = ncnt + NNODES;                   // [NNODES][CAP]
    int* vcnt = nidx + NNODES * CAP;
    int* vidx = vcnt + NVARS;                    // [NVARS][CAP]
    int* bar  = vidx + NVARS * CAP;              // 8 shards (64B apart) + release word
    uintptr_t wb = (uintptr_t)(bar + 144);
    wb = (wb + 15) & ~(uintptr_t)15;
    f16* wm_hi = (f16*)wb;            // 8*16384
    f16* vu_hi = wm_hi + 131072;      // 512*256
    f16* nu_hi = vu_hi + 131072;

    p.t1a = t1a; p.t1b = t1b; p.bar = bar;
    p.ncnt = ncnt; p.nidx = nidx; p.vcnt = vcnt; p.vidx = vidx;
    p.wm_hi = wm_hi; p.vu_hi = vu_hi; p.nu_hi = nu_hi;
    p.out = (float*)d_out;

    (void)hipMemsetAsync(vcnt, 0, NVARS * sizeof(int), stream);
    (void)hipMemsetAsync(bar, 0, 144 * sizeof(int), stream);

    BuildAll ba;
    ba.up = (const unsigned int*)d_in[1];
    ba.ncnt = ncnt; ba.nidx = nidx; ba.vcnt = vcnt; ba.vidx = vidx;
    ba.msrc[0] = (const float*)d_in[6];  ba.msrc[1] = (const float*)d_in[8];
    ba.msrc[2] = (const float*)d_in[10]; ba.msrc[3] = (const float*)d_in[12];
    ba.msrc[4] = (const float*)d_in[14]; ba.msrc[5] = (const float*)d_in[16];
    ba.msrc[6] = (const float*)d_in[18]; ba.msrc[7] = (const float*)d_in[20];
    ba.vu_wih = (const float*)d_in[24]; ba.vu_whh = (const float*)d_in[25];
    ba.nu_wih = (const float*)d_in[28]; ba.nu_whh = (const float*)d_in[29];
    ba.wm = wm_hi; ba.vu = vu_hi; ba.nu = nu_hi;
    build_all<<<NNODES + 1536, CTPB, 0, stream>>>(ba);

    mega<<<NB, TPB, 0, stream>>>(p);
}